// Round 11
// baseline (61.471 us; speedup 1.0000x reference)
//
#include <hip/hip_runtime.h>

#define B_   16
#define C_   3
#define H_   64
#define W_   64
#define K_   32
#define S_   16
#define OH_  60
#define OW_  60
#define P_   3600

#define KG   4                  // k's per block (one per wave)
#define NKG  (K_/KG)            // 8 k-groups
#define NBQ  4                  // batch-quarters (4 batches per block)
#define ROWS (C_*5)             // 15 (c, rh) rows per oh-stripe
#define BP   4                  // batches staged per block
#define ROWSTRIDE (W_*BP)       // 256 floats
#define XLDS (ROWS*ROWSTRIDE)   // 3840 floats = 15.36 KB

// TLP restructure (R10 was latency-bound at 27% occupancy, both pipes idle):
// 4-batch blocks -> ~18 KB LDS -> 8 blocks/CU capacity, grid 1920 = 7.5/CU
// ~= 30 waves/CU co-resident (2x R10). Lane = ow; leaf read = one b128
// (the block's whole batch-quad). Banks: read (4*ow+j)&31 -> 2-way = free;
// stage store bank = lane -> 2-way = free.
__device__ __forceinline__ float gate(float4 c, float a, float b) {
    return fmaf(fmaf(c.w, a, c.z), b, fmaf(c.y, a, c.x));
}

__global__ __launch_bounds__(256, 8) void logic_fused_kernel(
    const float* __restrict__ x,
    const int* __restrict__ ah, const int* __restrict__ aw, const int* __restrict__ ac,
    const int* __restrict__ bh_, const int* __restrict__ bw_, const int* __restrict__ bc_,
    const float* __restrict__ w0, const float* __restrict__ w1,
    const float* __restrict__ w2, const float* __restrict__ w3,
    const float* __restrict__ w4,
    float* __restrict__ out)
{
    __shared__ float  xs[XLDS];
    __shared__ float4 cf[KG * 31];
    __shared__ int    bAi[KG * S_], bBi[KG * S_];

    const int oh  = blockIdx.x;
    const int bq  = blockIdx.y;          // batch quarter: batches bq*4 .. bq*4+3
    const int kg  = blockIdx.z;
    const int tid = threadIdx.x;
    const int l   = tid & 63;
    const int wv  = tid >> 6;            // 0..3

    // ---- stage: 60 jobs (row 15 x w-16-block 4); lane = (w0 = l>>2, b = l&3)
    {
        const int b  = l & 3;
        const int w0 = l >> 2;           // 0..15
        const int gb = bq * 4 + b;
        for (int job = wv; job < ROWS * 4; job += 4) {
            int wb  = job & 3;
            int row = job >> 2;          // 0..14 = c*5 + dh
            int c   = row >= 10 ? 2 : (row >= 5 ? 1 : 0);
            int dh  = row - 5 * c;
            int w   = w0 + 16 * wb;
            xs[row * ROWSTRIDE + w * BP + b] =
                x[((gb * C_ + c) * H_ + (oh + dh)) * W_ + w];
        }
    }

    // ---- coefs (threads 0..127) and base offsets (threads 128..255)
    if (tid < 128) {
        int node = tid & 31, kk = tid >> 5;
        if (node < 31) {
            int k = kg * KG + kk;
            const float* w; int i;
            if      (node < 16) { w = w0; i = node;      }
            else if (node < 24) { w = w1; i = node - 16; }
            else if (node < 28) { w = w2; i = node - 24; }
            else if (node < 30) { w = w3; i = node - 28; }
            else                { w = w4; i = 0;         }
            const float* src = w + ((size_t)i * K_ + k) * 16;
            float lg[16];
            float m = -1e30f;
#pragma unroll
            for (int s = 0; s < 16; ++s) { lg[s] = src[s]; m = fmaxf(m, lg[s]); }
            float sum = 0.f;
#pragma unroll
            for (int s = 0; s < 16; ++s) { lg[s] = expf(lg[s] - m); sum += lg[s]; }
            float inv = 1.f / sum;
            const float M[16][4] = {
                {0,0,0,0},{0,0,0,1},{0,1,0,-1},{0,1,0,0},
                {0,0,1,-1},{0,0,1,0},{0,1,1,-2},{0,1,1,-1},
                {1,-1,-1,1},{1,-1,-1,2},{1,0,-1,0},{1,0,-1,1},
                {1,-1,0,0},{1,-1,0,1},{1,0,0,-1},{1,0,0,0}};
            float c0 = 0.f, c1 = 0.f, c2 = 0.f, c3 = 0.f;
#pragma unroll
            for (int s = 0; s < 16; ++s) {
                float pr = lg[s] * inv;
                c0 += pr * M[s][0]; c1 += pr * M[s][1];
                c2 += pr * M[s][2]; c3 += pr * M[s][3];
            }
            cf[kk * 31 + node] = make_float4(c0, c1, c2, c3);
        }
    } else {
        int i = tid - 128;               // 0..127
        int s = i & 15;
        if (i < 64) {
            int kk = i >> 4;             // 0..3
            int k  = kg * KG + kk;
            int idx = k * (P_ * 16) + s; // p = 0 slice -> relative offsets
            bAi[kk * 16 + s] = (ac[idx] * 5 + ah[idx]) * ROWSTRIDE + aw[idx] * BP;
        } else {
            int kk = (i - 64) >> 4;
            int k  = kg * KG + kk;
            int idx = k * (P_ * 16) + s;
            bBi[kk * 16 + s] = (bc_[idx] * 5 + bh_[idx]) * ROWSTRIDE + bw_[idx] * BP;
        }
    }
    __syncthreads();

    // ---- compute: wave wv -> k = kg*4 + wv; lane = ow (helpers 60..63 clamp)
    const int k      = kg * KG + wv;
    const int ow     = l;
    const int ow_eff = ow < OW_ ? ow : OW_ - 1;  // clamped lanes: same-addr
    const int lo     = ow_eff * BP;              // broadcast dup -> no conflict

    int baseA[S_], baseB[S_];            // wave-uniform -> SGPR
#pragma unroll
    for (int s = 0; s < S_; ++s) {
        baseA[s] = __builtin_amdgcn_readfirstlane(bAi[wv * 16 + s]);
        baseB[s] = __builtin_amdgcn_readfirstlane(bBi[wv * 16 + s]);
    }

    const float4* cfw = &cf[wv * 31];

    float t[4][8];                       // after fused leaf+level-1
#pragma unroll
    for (int i = 0; i < 8; ++i) {
        float4 a0 = *(const float4*)&xs[baseA[2*i]   + lo];
        float4 b0 = *(const float4*)&xs[baseB[2*i]   + lo];
        float4 a1 = *(const float4*)&xs[baseA[2*i+1] + lo];
        float4 b1 = *(const float4*)&xs[baseB[2*i+1] + lo];
        float4 c0 = cfw[2*i], c1 = cfw[2*i+1];
        float4 d  = cfw[16 + i];
        {
            float la = gate(c0, a0.x, b0.x), lb = gate(c1, a1.x, b1.x);
            t[0][i] = gate(d, la, lb);
        }
        {
            float la = gate(c0, a0.y, b0.y), lb = gate(c1, a1.y, b1.y);
            t[1][i] = gate(d, la, lb);
        }
        {
            float la = gate(c0, a0.z, b0.z), lb = gate(c1, a1.z, b1.z);
            t[2][i] = gate(d, la, lb);
        }
        {
            float la = gate(c0, a0.w, b0.w), lb = gate(c1, a1.w, b1.w);
            t[3][i] = gate(d, la, lb);
        }
    }
#pragma unroll
    for (int i = 0; i < 4; ++i) {
        float4 c = cfw[24 + i];
#pragma unroll
        for (int j = 0; j < 4; ++j)
            t[j][i] = gate(c, t[j][2*i], t[j][2*i+1]);
    }
#pragma unroll
    for (int i = 0; i < 2; ++i) {
        float4 c = cfw[28 + i];
#pragma unroll
        for (int j = 0; j < 4; ++j)
            t[j][i] = gate(c, t[j][2*i], t[j][2*i+1]);
    }
    {
        float4 c = cfw[30];
        if (ow < OW_) {
            const int obase = k * P_ + oh * OW_ + ow;
#pragma unroll
            for (int j = 0; j < 4; ++j) {
                float r = gate(c, t[j][0], t[j][1]);
                out[(size_t)(bq * 4 + j) * (K_ * P_) + obase] = r;
            }
        }
    }
}

extern "C" void kernel_launch(void* const* d_in, const int* in_sizes, int n_in,
                              void* d_out, int out_size, void* d_ws, size_t ws_size,
                              hipStream_t stream) {
    const float* x  = (const float*)d_in[0];
    const int* ah = (const int*)d_in[1];
    const int* aw = (const int*)d_in[2];
    const int* ac = (const int*)d_in[3];
    const int* bh = (const int*)d_in[4];
    const int* bw = (const int*)d_in[5];
    const int* bc = (const int*)d_in[6];
    const float* w0 = (const float*)d_in[7];
    const float* w1 = (const float*)d_in[8];
    const float* w2 = (const float*)d_in[9];
    const float* w3 = (const float*)d_in[10];
    const float* w4 = (const float*)d_in[11];
    float* out = (float*)d_out;

    dim3 grid(OH_, NBQ, NKG);
    logic_fused_kernel<<<grid, 256, 0, stream>>>(x, ah, aw, ac, bh, bw, bc,
                                                 w0, w1, w2, w3, w4, out);
}

// Round 12
// 30.190 us; speedup vs baseline: 2.0361x; 2.0361x over previous
//
#include <hip/hip_runtime.h>

#define B_   16
#define C_   3
#define H_   64
#define W_   64
#define K_   32
#define S_   16
#define OH_  60
#define OW_  60
#define P_   3600

#define KG   4                  // k's per block (one per wave)
#define NKG  (K_/KG)            // 8 k-groups
#define NBQ  4                  // batch-quarters (4 batches per block)
#define ROWS (C_*5)             // 15 (c, rh) rows per oh-stripe
#define BP   4                  // batches staged per block
#define ROWSTRIDE (W_*BP)       // 256 floats
#define XLDS (ROWS*ROWSTRIDE)   // 3840 floats = 15.36 KB

// R11 lesson (rule #20 variant): __launch_bounds__(256,8) capped VGPR at 32
// -> ~190MB of scratch spill traffic (FETCH 71MB, WRITE 146MB), kernel 65us.
// (256,4) gives the allocator 128 VGPR headroom (body needs ~64); LDS
// (17.9KB) remains the occupancy limiter at 8 blocks/CU = 32 waves/CU.
__device__ __forceinline__ float gate(float4 c, float a, float b) {
    return fmaf(fmaf(c.w, a, c.z), b, fmaf(c.y, a, c.x));
}

__global__ __launch_bounds__(256, 4) void logic_fused_kernel(
    const float* __restrict__ x,
    const int* __restrict__ ah, const int* __restrict__ aw, const int* __restrict__ ac,
    const int* __restrict__ bh_, const int* __restrict__ bw_, const int* __restrict__ bc_,
    const float* __restrict__ w0, const float* __restrict__ w1,
    const float* __restrict__ w2, const float* __restrict__ w3,
    const float* __restrict__ w4,
    float* __restrict__ out)
{
    __shared__ float  xs[XLDS];
    __shared__ float4 cf[KG * 31];
    __shared__ int    bAi[KG * S_], bBi[KG * S_];

    const int oh  = blockIdx.x;
    const int bq  = blockIdx.y;          // batch quarter: batches bq*4 .. bq*4+3
    const int kg  = blockIdx.z;
    const int tid = threadIdx.x;
    const int l   = tid & 63;
    const int wv  = tid >> 6;            // 0..3

    // ---- stage: 60 jobs (row 15 x w-16-block 4); lane = (w0 = l>>2, b = l&3)
    {
        const int b  = l & 3;
        const int w0 = l >> 2;           // 0..15
        const int gb = bq * 4 + b;
        for (int job = wv; job < ROWS * 4; job += 4) {
            int wb  = job & 3;
            int row = job >> 2;          // 0..14 = c*5 + dh
            int c   = row >= 10 ? 2 : (row >= 5 ? 1 : 0);
            int dh  = row - 5 * c;
            int w   = w0 + 16 * wb;
            xs[row * ROWSTRIDE + w * BP + b] =
                x[((gb * C_ + c) * H_ + (oh + dh)) * W_ + w];
        }
    }

    // ---- coefs (threads 0..127) and base offsets (threads 128..255)
    if (tid < 128) {
        int node = tid & 31, kk = tid >> 5;
        if (node < 31) {
            int k = kg * KG + kk;
            const float* w; int i;
            if      (node < 16) { w = w0; i = node;      }
            else if (node < 24) { w = w1; i = node - 16; }
            else if (node < 28) { w = w2; i = node - 24; }
            else if (node < 30) { w = w3; i = node - 28; }
            else                { w = w4; i = 0;         }
            const float* src = w + ((size_t)i * K_ + k) * 16;
            float lg[16];
            float m = -1e30f;
#pragma unroll
            for (int s = 0; s < 16; ++s) { lg[s] = src[s]; m = fmaxf(m, lg[s]); }
            float sum = 0.f;
#pragma unroll
            for (int s = 0; s < 16; ++s) { lg[s] = expf(lg[s] - m); sum += lg[s]; }
            float inv = 1.f / sum;
            const float M[16][4] = {
                {0,0,0,0},{0,0,0,1},{0,1,0,-1},{0,1,0,0},
                {0,0,1,-1},{0,0,1,0},{0,1,1,-2},{0,1,1,-1},
                {1,-1,-1,1},{1,-1,-1,2},{1,0,-1,0},{1,0,-1,1},
                {1,-1,0,0},{1,-1,0,1},{1,0,0,-1},{1,0,0,0}};
            float c0 = 0.f, c1 = 0.f, c2 = 0.f, c3 = 0.f;
#pragma unroll
            for (int s = 0; s < 16; ++s) {
                float pr = lg[s] * inv;
                c0 += pr * M[s][0]; c1 += pr * M[s][1];
                c2 += pr * M[s][2]; c3 += pr * M[s][3];
            }
            cf[kk * 31 + node] = make_float4(c0, c1, c2, c3);
        }
    } else {
        int i = tid - 128;               // 0..127
        int s = i & 15;
        if (i < 64) {
            int kk = i >> 4;             // 0..3
            int k  = kg * KG + kk;
            int idx = k * (P_ * 16) + s; // p = 0 slice -> relative offsets
            bAi[kk * 16 + s] = (ac[idx] * 5 + ah[idx]) * ROWSTRIDE + aw[idx] * BP;
        } else {
            int kk = (i - 64) >> 4;
            int k  = kg * KG + kk;
            int idx = k * (P_ * 16) + s;
            bBi[kk * 16 + s] = (bc_[idx] * 5 + bh_[idx]) * ROWSTRIDE + bw_[idx] * BP;
        }
    }
    __syncthreads();

    // ---- compute: wave wv -> k = kg*4 + wv; lane = ow (helpers 60..63 clamp)
    const int k      = kg * KG + wv;
    const int ow     = l;
    const int ow_eff = ow < OW_ ? ow : OW_ - 1;  // clamped lanes: same-addr
    const int lo     = ow_eff * BP;              // broadcast dup -> no conflict

    int baseA[S_], baseB[S_];            // wave-uniform -> SGPR
#pragma unroll
    for (int s = 0; s < S_; ++s) {
        baseA[s] = __builtin_amdgcn_readfirstlane(bAi[wv * 16 + s]);
        baseB[s] = __builtin_amdgcn_readfirstlane(bBi[wv * 16 + s]);
    }

    const float4* cfw = &cf[wv * 31];

    float t[4][8];                       // after fused leaf+level-1
#pragma unroll
    for (int i = 0; i < 8; ++i) {
        float4 a0 = *(const float4*)&xs[baseA[2*i]   + lo];
        float4 b0 = *(const float4*)&xs[baseB[2*i]   + lo];
        float4 a1 = *(const float4*)&xs[baseA[2*i+1] + lo];
        float4 b1 = *(const float4*)&xs[baseB[2*i+1] + lo];
        float4 c0 = cfw[2*i], c1 = cfw[2*i+1];
        float4 d  = cfw[16 + i];
        {
            float la = gate(c0, a0.x, b0.x), lb = gate(c1, a1.x, b1.x);
            t[0][i] = gate(d, la, lb);
        }
        {
            float la = gate(c0, a0.y, b0.y), lb = gate(c1, a1.y, b1.y);
            t[1][i] = gate(d, la, lb);
        }
        {
            float la = gate(c0, a0.z, b0.z), lb = gate(c1, a1.z, b1.z);
            t[2][i] = gate(d, la, lb);
        }
        {
            float la = gate(c0, a0.w, b0.w), lb = gate(c1, a1.w, b1.w);
            t[3][i] = gate(d, la, lb);
        }
    }
#pragma unroll
    for (int i = 0; i < 4; ++i) {
        float4 c = cfw[24 + i];
#pragma unroll
        for (int j = 0; j < 4; ++j)
            t[j][i] = gate(c, t[j][2*i], t[j][2*i+1]);
    }
#pragma unroll
    for (int i = 0; i < 2; ++i) {
        float4 c = cfw[28 + i];
#pragma unroll
        for (int j = 0; j < 4; ++j)
            t[j][i] = gate(c, t[j][2*i], t[j][2*i+1]);
    }
    {
        float4 c = cfw[30];
        if (ow < OW_) {
            const int obase = k * P_ + oh * OW_ + ow;
#pragma unroll
            for (int j = 0; j < 4; ++j) {
                float r = gate(c, t[j][0], t[j][1]);
                out[(size_t)(bq * 4 + j) * (K_ * P_) + obase] = r;
            }
        }
    }
}

extern "C" void kernel_launch(void* const* d_in, const int* in_sizes, int n_in,
                              void* d_out, int out_size, void* d_ws, size_t ws_size,
                              hipStream_t stream) {
    const float* x  = (const float*)d_in[0];
    const int* ah = (const int*)d_in[1];
    const int* aw = (const int*)d_in[2];
    const int* ac = (const int*)d_in[3];
    const int* bh = (const int*)d_in[4];
    const int* bw = (const int*)d_in[5];
    const int* bc = (const int*)d_in[6];
    const float* w0 = (const float*)d_in[7];
    const float* w1 = (const float*)d_in[8];
    const float* w2 = (const float*)d_in[9];
    const float* w3 = (const float*)d_in[10];
    const float* w4 = (const float*)d_in[11];
    float* out = (float*)d_out;

    dim3 grid(OH_, NBQ, NKG);
    logic_fused_kernel<<<grid, 256, 0, stream>>>(x, ah, aw, ac, bh, bw, bc,
                                                 w0, w1, w2, w3, w4, out);
}